// Round 14
// baseline (93.793 us; speedup 1.0000x reference)
//
#include <hip/hip_runtime.h>
#include <hip/hip_bf16.h>
#include <math.h>

// Problem constants (fixed by the reference): N=2048 nodes, E=32768 edges,
// C_IN=C_OUT=128, OH_CH=8, onehot row length L=2048.
#define NN   2048
#define LROW 2048
#define DEGCAP 128   // max senders per receiver (Poisson(16); cap is ~8 sigma out)

typedef __attribute__((ext_vector_type(8))) short short8;
typedef __attribute__((ext_vector_type(4))) float f32x4;
typedef unsigned int u32;

__device__ __forceinline__ unsigned short bf16b(float x) {
    __hip_bfloat16 h = __float2bfloat16(x);
    return *reinterpret_cast<unsigned short*>(&h);
}

// ---- packed fp16 helpers (raw u32 regs + VOP3P asm; avoids fp16/bf16 header clash)

__device__ __forceinline__ u32 pkmin(u32 a, u32 b) {
    u32 d; asm("v_pk_min_f16 %0, %1, %2" : "=v"(d) : "v"(a), "v"(b)); return d;
}
__device__ __forceinline__ u32 pkmax(u32 a, u32 b) {
    u32 d; asm("v_pk_max_f16 %0, %1, %2" : "=v"(d) : "v"(a), "v"(b)); return d;
}
__device__ __forceinline__ u32 packf2(float lo, float hi) {
    union { _Float16 h[2]; u32 u; } c;
    c.h[0] = (_Float16)lo; c.h[1] = (_Float16)hi;
    return c.u;
}
__device__ __forceinline__ float unpk_lo(u32 v) {
    union { u32 u; _Float16 h[2]; } c; c.u = v; return (float)c.h[0];
}
__device__ __forceinline__ float unpk_hi(u32 v) {
    union { u32 u; _Float16 h[2]; } c; c.u = v; return (float)c.h[1];
}

// ---------------- prep: onehot f32->bf16 (rows) + adjacency fill (tail blocks) ----

__global__ __launch_bounds__(256) void prep_k(
        const float* __restrict__ oh, unsigned short* __restrict__ ohbf,
        const int* __restrict__ send, const int* __restrict__ recv,
        int* __restrict__ cnt, int* __restrict__ elist2, int E) {
    const int bid = blockIdx.x;
    if (bid < NN) {
        int base = bid * 2048 + threadIdx.x * 8;
        float4 f0 = *(const float4*)(oh + base);
        float4 f1 = *(const float4*)(oh + base + 4);
        union { short8 s8; unsigned short us[8]; } pk;
        pk.us[0] = bf16b(f0.x); pk.us[1] = bf16b(f0.y);
        pk.us[2] = bf16b(f0.z); pk.us[3] = bf16b(f0.w);
        pk.us[4] = bf16b(f1.x); pk.us[5] = bf16b(f1.y);
        pk.us[6] = bf16b(f1.z); pk.us[7] = bf16b(f1.w);
        *(short8*)(ohbf + base) = pk.s8;
    } else {
        int i = (bid - NN) * 256 + threadIdx.x;
        if (i < E) {
            int r = recv[i];
            int slot = atomicAdd(&cnt[r], 1);
            if (slot < DEGCAP) elist2[r * DEGCAP + slot] = send[i];
        }
    }
}

// ---------------- bitonic helpers ----------------

__device__ __forceinline__ void ce(float& a, float& b, bool up) {
    float lo = fminf(a, b), hi = fmaxf(a, b);
    a = up ? lo : hi;
    b = up ? hi : lo;
}

__device__ __forceinline__ void ce_pk(u32& a, u32& b, bool up) {
    u32 mn = pkmin(a, b), mx = pkmax(a, b);
    a = up ? mn : mx;
    b = up ? mx : mn;
}

// merge a bitonic 8-seq held as 4 packed-fp16 u32 regs (dir uniform per thread)
__device__ __forceinline__ void merge8_pk(u32 h[4], bool up) {
    ce_pk(h[0], h[2], up); ce_pk(h[1], h[3], up);   // j=4
    ce_pk(h[0], h[1], up); ce_pk(h[2], h[3], up);   // j=2
#pragma unroll
    for (int m = 0; m < 4; ++m) {                    // j=1 within reg
        u32 hs = (h[m] >> 16) | (h[m] << 16);
        u32 mn = pkmin(h[m], hs);                    // both lanes = min
        u32 mx = pkmax(h[m], hs);                    // both lanes = max
        u32 ru = __builtin_amdgcn_perm(mx, mn, 0x07060100u); // [mn.lo, mx.hi] asc
        u32 rd = __builtin_amdgcn_perm(mn, mx, 0x07060100u); // [mx.lo, mn.hi] desc
        h[m] = up ? ru : rd;
    }
}

__device__ __forceinline__ short8 conv1pack(float xm, float x0v, float xp,
        const float* __restrict__ cw1, const float* __restrict__ cb1) {
    union { short8 s8; unsigned short us[8]; } pk;
#pragma unroll
    for (int c = 0; c < 8; ++c) {
        float w = cb1[c] + cw1[c * 3] * xm + cw1[c * 3 + 1] * x0v + cw1[c * 3 + 2] * xp;
        pk.us[c] = bf16b(w > 0.f ? w : 0.f);
    }
    return pk.s8;
}

// ---- per-row conv + readout + lin1 (called twice; smem reused, barrier-guarded)

__device__ __forceinline__ void conv_row(
        const u32 h[4], float myagg, int r, int tid, int lane, int wv,
        float* sf, unsigned short* h1t,
        float (*red)[16], float* u, float* lpart,
        short8 afrag, float bs0, float bs1, float bs2, float bs3,
        const float* __restrict__ cw1, const float* __restrict__ cb1,
        const float* __restrict__ Wr,  const float* __restrict__ br,
        const float* __restrict__ W1,  const float* __restrict__ b1,
        float* __restrict__ t) {
    const int col = tid * 8;
    float v[8];
    v[0] = unpk_lo(h[0]); v[1] = unpk_hi(h[0]);
    v[2] = unpk_lo(h[1]); v[3] = unpk_hi(h[1]);
    v[4] = unpk_lo(h[2]); v[5] = unpk_hi(h[2]);
    v[6] = unpk_lo(h[3]); v[7] = unpk_hi(h[3]);

    // stage sorted row; fetch chunk-edge neighbors
    __syncthreads();   // previous smem users done
    *(float4*)&sf[col]     = make_float4(v[0], v[1], v[2], v[3]);
    *(float4*)&sf[col + 4] = make_float4(v[4], v[5], v[6], v[7]);
    __syncthreads();
    float lf1 = (tid == 0)   ? 0.f : sf[col - 1];
    float rt1 = (tid == 255) ? 0.f : sf[col + 8];

    float s0 = 0.f, s1 = 0.f, s2 = 0.f, s3 = 0.f;
    f32x4 zero = {0.f, 0.f, 0.f, 0.f};

#pragma unroll 1
    for (int half = 0; half < 2; ++half) {
        __syncthreads();   // previous phase's LDS reads (sf or MFMA) complete
        if ((tid >> 7) == half) {
            const int lt = tid & 127;
#pragma unroll
            for (int p = 0; p < 8; ++p) {
                float xm  = (p == 0) ? lf1 : v[p - 1];
                float x0v = v[p];
                float xp  = (p == 7) ? rt1 : v[p + 1];
                int uu = lt * 8 + p + 1;
                int us = uu ^ ((uu >> 3) & 7);
                *(short8*)&h1t[us * 8] = conv1pack(xm, x0v, xp, cw1, cb1);
            }
        }
        if (half == 0) {
            if (tid == 128)   // h1[1024] (slot 1025): xm=s[1023]=lf1
                *(short8*)&h1t[1025 * 8] = conv1pack(lf1, v[0], v[1], cw1, cb1);
            if (tid == 0) {   // h1[-1] = 0
                short8 z = {0, 0, 0, 0, 0, 0, 0, 0};
                *(short8*)&h1t[0] = z;
            }
            if (tid == 1) {   // d=3 overreach slots: must be finite (A row is 0)
                short8 z = {0, 0, 0, 0, 0, 0, 0, 0};
                *(short8*)&h1t[1026 * 8] = z;
                *(short8*)&h1t[1027 * 8] = z;
            }
        } else {
            if (tid == 127)   // h1[1023] (slot 0): xp=s[1024]=rt1
                *(short8*)&h1t[0] = conv1pack(v[6], v[7], rt1, cw1, cb1);
            if (tid == 0) {   // h1[2048] = 0
                short8 z = {0, 0, 0, 0, 0, 0, 0, 0};
                *(short8*)&h1t[1025 * 8] = z;
            }
        }
        __syncthreads();

#pragma unroll 4
        for (int i = 0; i < 16; ++i) {
            int lp = (wv * 16 + i) * 16 + (lane & 15);   // local position 0..1023
            int uu = lp + (lane >> 4);                   // slot = local_pos + d
            int us = uu ^ ((uu >> 3) & 7);
            short8 bfrag = *(const short8*)&h1t[us * 8];
            f32x4 d = __builtin_amdgcn_mfma_f32_16x16x32_bf16(afrag, bfrag, zero, 0, 0, 0);
            s0 += fmaxf(d[0] + bs0, 0.f);
            s1 += fmaxf(d[1] + bs1, 0.f);
            s2 += fmaxf(d[2] + bs2, 0.f);
            s3 += fmaxf(d[3] + bs3, 0.f);
        }
    }

    // reduce over the 16 column-lanes (positions)
#pragma unroll
    for (int off = 1; off < 16; off <<= 1) {
        s0 += __shfl_xor(s0, off);
        s1 += __shfl_xor(s1, off);
        s2 += __shfl_xor(s2, off);
        s3 += __shfl_xor(s3, off);
    }
    const int mb = (lane >> 4) * 4;
    if ((lane & 15) == 0) {
        red[wv][mb + 0] = s0; red[wv][mb + 1] = s1;
        red[wv][mb + 2] = s2; red[wv][mb + 3] = s3;
    }
    if (tid < 128) u[tid] = myagg;
    __syncthreads();

    // readout = mean @ Wr + br
    if (tid < 8) {
        float acc = br[tid];
#pragma unroll
        for (int c = 0; c < 16; ++c) {
            float tot = red[0][c] + red[1][c] + red[2][c] + red[3][c];
            acc += (tot * (1.0f / (float)LROW)) * Wr[c * 8 + tid];
        }
        u[128 + tid] = acc;
    }
    __syncthreads();

    // lin1: t[r] = concat(aggx, readout) @ W1 + b1
    {
        const int jc = tid & 127, hf = tid >> 7;
        float acc = (hf == 0) ? b1[jc] : 0.f;
        const int c0 = hf * 68;
#pragma unroll 4
        for (int c = 0; c < 68; ++c) acc += u[c0 + c] * W1[(size_t)(c0 + c) * 128 + jc];
        if (hf) lpart[jc] = acc;
        __syncthreads();
        if (!hf) t[(size_t)r * 128 + jc] = acc + lpart[jc];
    }
}

// ---------------- fused, TWO rows per block: gather + packed sort (2x ILP)
//                  + conv(MFMA) + lin1 ----------

template<int BF>
__global__ __launch_bounds__(256, 6) void fused2_k(
        const float* __restrict__ oh, const unsigned short* __restrict__ ohbf,
        const float* __restrict__ x,
        const int* __restrict__ elist2, const int* __restrict__ cnt,
        float* __restrict__ newoh, float* __restrict__ t,
        const float* __restrict__ cw1, const float* __restrict__ cb1,
        const float* __restrict__ cw2, const float* __restrict__ cb2,
        const float* __restrict__ Wr,  const float* __restrict__ br,
        const float* __restrict__ W1,  const float* __restrict__ b1) {
    // time-shared: sort staging (2 rows x 4KB), sf (8KB), h1t (16448 B)
    __shared__ __align__(16) char smem[1028 * 16];
    float* sf = (float*)smem;
    u32* sfu = (u32*)smem;
    unsigned short* h1t = (unsigned short*)smem;
    __shared__ unsigned short a_lds[16 * 32];
    __shared__ float red[4][16];
    __shared__ float u[136];
    __shared__ float lpart[128];

    const int tid = threadIdx.x;
    const int lane = tid & 63, wv = tid >> 6;
    const int col = tid * 8;
    const int rA = blockIdx.x * 2, rB = rA + 1;

    // ---- build bf16 A tile: [16 c2][32 k], k = 8*d + c1 ----
    for (int i = tid; i < 512; i += 256) {
        int c2 = i >> 5, k = i & 31, d = k >> 3, c1 = k & 7;
        float w = (d < 3) ? cw2[(c2 * 8 + c1) * 3 + d] : 0.f;
        a_lds[i] = bf16b(w);
    }

    u32 hA[4], hB[4];
    float myaggA = 0.f, myaggB = 0.f;

    // ---- gather + f32 k=2..8 rounds + pack, per row ----
#pragma unroll 1
    for (int row = 0; row < 2; ++row) {
        const int r = row ? rB : rA;
        float v[8];
        {
            float4 b0 = *(const float4*)(oh + (size_t)r * LROW + col);
            float4 b1v = *(const float4*)(oh + (size_t)r * LROW + col + 4);
            v[0] = b0.x;  v[1] = b0.y;  v[2] = b0.z;  v[3] = b0.w;
            v[4] = b1v.x; v[5] = b1v.y; v[6] = b1v.z; v[7] = b1v.w;
        }
        float myagg = 0.f;
        const int deg = min(cnt[r], DEGCAP);
        const int* my = elist2 + r * DEGCAP;
        int e = 0;
        if (BF) {
            for (; e + 4 <= deg; e += 4) {
                int se0 = my[e], se1 = my[e + 1], se2 = my[e + 2], se3 = my[e + 3];
                uint4 ua = *((const uint4*)(ohbf + (size_t)se0 * LROW) + tid);
                uint4 ub = *((const uint4*)(ohbf + (size_t)se1 * LROW) + tid);
                uint4 uc = *((const uint4*)(ohbf + (size_t)se2 * LROW) + tid);
                uint4 ud = *((const uint4*)(ohbf + (size_t)se3 * LROW) + tid);
                float xa = 0.f, xb = 0.f, xc = 0.f, xd = 0.f;
                if (tid < 128) {
                    xa = x[(size_t)se0 * 128 + tid]; xb = x[(size_t)se1 * 128 + tid];
                    xc = x[(size_t)se2 * 128 + tid]; xd = x[(size_t)se3 * 128 + tid];
                }
                v[0] += __uint_as_float(ua.x << 16); v[1] += __uint_as_float(ua.x & 0xffff0000u);
                v[2] += __uint_as_float(ua.y << 16); v[3] += __uint_as_float(ua.y & 0xffff0000u);
                v[4] += __uint_as_float(ua.z << 16); v[5] += __uint_as_float(ua.z & 0xffff0000u);
                v[6] += __uint_as_float(ua.w << 16); v[7] += __uint_as_float(ua.w & 0xffff0000u);
                v[0] += __uint_as_float(ub.x << 16); v[1] += __uint_as_float(ub.x & 0xffff0000u);
                v[2] += __uint_as_float(ub.y << 16); v[3] += __uint_as_float(ub.y & 0xffff0000u);
                v[4] += __uint_as_float(ub.z << 16); v[5] += __uint_as_float(ub.z & 0xffff0000u);
                v[6] += __uint_as_float(ub.w << 16); v[7] += __uint_as_float(ub.w & 0xffff0000u);
                v[0] += __uint_as_float(uc.x << 16); v[1] += __uint_as_float(uc.x & 0xffff0000u);
                v[2] += __uint_as_float(uc.y << 16); v[3] += __uint_as_float(uc.y & 0xffff0000u);
                v[4] += __uint_as_float(uc.z << 16); v[5] += __uint_as_float(uc.z & 0xffff0000u);
                v[6] += __uint_as_float(uc.w << 16); v[7] += __uint_as_float(uc.w & 0xffff0000u);
                v[0] += __uint_as_float(ud.x << 16); v[1] += __uint_as_float(ud.x & 0xffff0000u);
                v[2] += __uint_as_float(ud.y << 16); v[3] += __uint_as_float(ud.y & 0xffff0000u);
                v[4] += __uint_as_float(ud.z << 16); v[5] += __uint_as_float(ud.z & 0xffff0000u);
                v[6] += __uint_as_float(ud.w << 16); v[7] += __uint_as_float(ud.w & 0xffff0000u);
                myagg += xa; myagg += xb; myagg += xc; myagg += xd;
            }
            for (; e < deg; ++e) {
                int se = my[e];
                uint4 ua = *((const uint4*)(ohbf + (size_t)se * LROW) + tid);
                if (tid < 128) myagg += x[(size_t)se * 128 + tid];
                v[0] += __uint_as_float(ua.x << 16); v[1] += __uint_as_float(ua.x & 0xffff0000u);
                v[2] += __uint_as_float(ua.y << 16); v[3] += __uint_as_float(ua.y & 0xffff0000u);
                v[4] += __uint_as_float(ua.z << 16); v[5] += __uint_as_float(ua.z & 0xffff0000u);
                v[6] += __uint_as_float(ua.w << 16); v[7] += __uint_as_float(ua.w & 0xffff0000u);
            }
        } else {
            for (; e < deg; ++e) {
                int se = my[e];
                float4 c0 = *(const float4*)(oh + (size_t)se * LROW + col);
                float4 c1 = *(const float4*)(oh + (size_t)se * LROW + col + 4);
                if (tid < 128) myagg += x[(size_t)se * 128 + tid];
                v[0] += c0.x; v[1] += c0.y; v[2] += c0.z; v[3] += c0.w;
                v[4] += c1.x; v[5] += c1.y; v[6] += c1.z; v[7] += c1.w;
            }
        }
        // write new_oh (output) straight from the exact f32 accumulators
        *(float4*)(newoh + (size_t)r * LROW + col)     = make_float4(v[0], v[1], v[2], v[3]);
        *(float4*)(newoh + (size_t)r * LROW + col + 4) = make_float4(v[4], v[5], v[6], v[7]);

        // bitonic k=2..8 in f32
        ce(v[0], v[1], true);  ce(v[2], v[3], false); ce(v[4], v[5], true);  ce(v[6], v[7], false);
        ce(v[0], v[2], true);  ce(v[1], v[3], true);  ce(v[4], v[6], false); ce(v[5], v[7], false);
        ce(v[0], v[1], true);  ce(v[2], v[3], true);  ce(v[4], v[5], false); ce(v[6], v[7], false);
        {
            bool up8 = (tid & 1) == 0;
            ce(v[0], v[4], up8); ce(v[1], v[5], up8); ce(v[2], v[6], up8); ce(v[3], v[7], up8);
            ce(v[0], v[2], up8); ce(v[1], v[3], up8); ce(v[4], v[6], up8); ce(v[5], v[7], up8);
            ce(v[0], v[1], up8); ce(v[2], v[3], up8); ce(v[4], v[5], up8); ce(v[6], v[7], up8);
        }
        if (row == 0) {
            hA[0] = packf2(v[0], v[1]); hA[1] = packf2(v[2], v[3]);
            hA[2] = packf2(v[4], v[5]); hA[3] = packf2(v[6], v[7]);
            myaggA = myagg;
        } else {
            hB[0] = packf2(v[0], v[1]); hB[1] = packf2(v[2], v[3]);
            hB[2] = packf2(v[4], v[5]); hB[3] = packf2(v[6], v[7]);
            myaggB = myagg;
        }
    }

    // ---- packed sort k=16..2048, BOTH rows interleaved (2x ILP per pass) ----
#pragma unroll
    for (int lk = 4; lk <= 11; ++lk) {
        const int k = 1 << lk;
        const bool up = ((tid & (k >> 3)) == 0);
#pragma unroll
        for (int lj = lk - 1; lj >= 3; --lj) {
            const int D = 1 << (lj - 3);
            const bool keepmin = (((tid & D) == 0) == up);
            if (D <= 32) {
#pragma unroll
                for (int m = 0; m < 4; ++m) {
                    u32 hsA = (u32)__shfl_xor((int)hA[m], D, 64);
                    u32 hsB = (u32)__shfl_xor((int)hB[m], D, 64);
                    hA[m] = keepmin ? pkmin(hA[m], hsA) : pkmax(hA[m], hsA);
                    hB[m] = keepmin ? pkmin(hB[m], hsB) : pkmax(hB[m], hsB);
                }
            } else {
                __syncthreads();
                *(uint4*)&sfu[tid * 4]        = make_uint4(hA[0], hA[1], hA[2], hA[3]);
                *(uint4*)&sfu[1024 + tid * 4] = make_uint4(hB[0], hB[1], hB[2], hB[3]);
                __syncthreads();
                uint4 PA = *(const uint4*)&sfu[(tid ^ D) * 4];
                uint4 PB = *(const uint4*)&sfu[1024 + (tid ^ D) * 4];
                hA[0] = keepmin ? pkmin(hA[0], PA.x) : pkmax(hA[0], PA.x);
                hA[1] = keepmin ? pkmin(hA[1], PA.y) : pkmax(hA[1], PA.y);
                hA[2] = keepmin ? pkmin(hA[2], PA.z) : pkmax(hA[2], PA.z);
                hA[3] = keepmin ? pkmin(hA[3], PA.w) : pkmax(hA[3], PA.w);
                hB[0] = keepmin ? pkmin(hB[0], PB.x) : pkmax(hB[0], PB.x);
                hB[1] = keepmin ? pkmin(hB[1], PB.y) : pkmax(hB[1], PB.y);
                hB[2] = keepmin ? pkmin(hB[2], PB.z) : pkmax(hB[2], PB.z);
                hB[3] = keepmin ? pkmin(hB[3], PB.w) : pkmax(hB[3], PB.w);
            }
        }
        merge8_pk(hA, up);
        merge8_pk(hB, up);
    }

    // ---- per-row conv + epilogue (smem reused serially, barrier-guarded) ----
    short8 afrag = *(const short8*)&a_lds[(lane & 15) * 32 + (lane >> 4) * 8];
    const int mb = (lane >> 4) * 4;
    const float bs0 = cb2[mb], bs1 = cb2[mb + 1], bs2 = cb2[mb + 2], bs3 = cb2[mb + 3];

    conv_row(hA, myaggA, rA, tid, lane, wv, sf, h1t, red, u, lpart,
             afrag, bs0, bs1, bs2, bs3, cw1, cb1, Wr, br, W1, b1, t);
    conv_row(hB, myaggB, rB, tid, lane, wv, sf, h1t, red, u, lpart,
             afrag, bs0, bs1, bs2, bs3, cw1, cb1, Wr, br, W1, b1, t);
}

// ---------------- BN stats stage 1, coalesced, deterministic ----------------

__global__ __launch_bounds__(256) void bnpart_k(const float* __restrict__ t,
                                                float* __restrict__ part) {
    const int b = blockIdx.x, tid = threadIdx.x;
    const int col = tid & 127, h = tid >> 7;
    float sm = 0.f, sq = 0.f;
    for (int i = 0; i < 32; ++i) {
        int row = b * 64 + h * 32 + i;
        float v = t[(size_t)row * 128 + col];
        sm += v; sq += v * v;
    }
    __shared__ float ps[2][128], pq[2][128];
    ps[h][col] = sm; pq[h][col] = sq;
    __syncthreads();
    if (h == 0) {
        part[(size_t)b * 256 + col]       = sm + ps[1][col];
        part[(size_t)b * 256 + 128 + col] = sq + pq[1][col];
    }
}

// ---------------- BN finalize (inline) + ReLU + @W2 + b2, 16 rows/block ----------

__global__ __launch_bounds__(256) void out_k(
        float* __restrict__ t, const float* __restrict__ part,
        const float* __restrict__ gamma, const float* __restrict__ beta,
        const float* __restrict__ W2, const float* __restrict__ b2) {
    __shared__ float u[16][128];
    __shared__ float sc_s[128], sh_s[128];
    const int r0 = blockIdx.x * 16, tid = threadIdx.x;
    if (tid < 128) {
        float sm = 0.f, sq = 0.f;
        for (int b = 0; b < 32; ++b) {
            sm += part[(size_t)b * 256 + tid];
            sq += part[(size_t)b * 256 + 128 + tid];
        }
        float mu  = sm / (float)NN;
        float var = sq / (float)NN - mu * mu;
        float sc  = rsqrtf(var + 1e-5f) * gamma[tid];
        sc_s[tid] = sc;
        sh_s[tid] = beta[tid] - mu * sc;
    }
    __syncthreads();
#pragma unroll
    for (int m = 0; m < 8; ++m) {
        int idx = tid + 256 * m;
        int rr = idx >> 7, c = idx & 127;
        float v = t[(size_t)(r0 + rr) * 128 + c];
        v = v * sc_s[c] + sh_s[c];
        u[rr][c] = v > 0.f ? v : 0.f;
    }
    __syncthreads();
    const int j = tid & 127, g = tid >> 7;
    float acc[8];
    float bb = b2[j];
#pragma unroll
    for (int rr = 0; rr < 8; ++rr) acc[rr] = bb;
    for (int c = 0; c < 128; ++c) {
        float w = W2[(size_t)c * 128 + j];
#pragma unroll
        for (int rr = 0; rr < 8; ++rr) acc[rr] += u[g * 8 + rr][c] * w;
    }
#pragma unroll
    for (int rr = 0; rr < 8; ++rr)
        t[(size_t)(r0 + g * 8 + rr) * 128 + j] = acc[rr];
}

// ---------------- launch ----------------

extern "C" void kernel_launch(void* const* d_in, const int* in_sizes, int n_in,
                              void* d_out, int out_size, void* d_ws, size_t ws_size,
                              hipStream_t stream) {
    const float* x      = (const float*)d_in[0];
    const float* onehot = (const float*)d_in[1];
    const int*   adj    = (const int*)d_in[2];
    // d_in[3] = n_nodes (scalar), fixed at 2048
    const float* W1     = (const float*)d_in[4];
    const float* b1     = (const float*)d_in[5];
    const float* gamma  = (const float*)d_in[6];
    const float* beta   = (const float*)d_in[7];
    const float* W2     = (const float*)d_in[8];
    const float* b2     = (const float*)d_in[9];
    const float* cw1    = (const float*)d_in[10];
    const float* cb1    = (const float*)d_in[11];
    const float* cw2    = (const float*)d_in[12];
    const float* cb2    = (const float*)d_in[13];
    const float* Wr     = (const float*)d_in[14];
    const float* br     = (const float*)d_in[15];

    const int E = in_sizes[2] / 2;
    const int* send = adj;
    const int* recv = adj + E;

    // workspace layout
    int*   cnt    = (int*)d_ws;                          // 2048 ints
    int*   elist2 = cnt + 2048;                          // 2048*DEGCAP ints
    float* part   = (float*)(elist2 + NN * DEGCAP);      // 32*256
    unsigned short* ohbf = (unsigned short*)(part + 32 * 256);  // 2048*2048 bf16
    size_t need = (size_t)((char*)(ohbf + (size_t)NN * LROW) - (char*)d_ws);
    const bool bf_path = (ws_size >= need);

    float* out_x2 = (float*)d_out;              // [2048,128] (staged pre-BN, then final)
    float* out_oh = out_x2 + (size_t)NN * 128;  // [2048,2048]

    hipMemsetAsync(cnt, 0, 2048 * sizeof(int), stream);

    if (bf_path) {
        prep_k<<<NN + (E + 255) / 256, 256, 0, stream>>>(onehot, ohbf, send, recv,
                                                         cnt, elist2, E);
        fused2_k<1><<<NN / 2, 256, 0, stream>>>(onehot, ohbf, x, elist2, cnt,
                                                out_oh, out_x2,
                                                cw1, cb1, cw2, cb2, Wr, br, W1, b1);
    } else {
        prep_k<<<NN + (E + 255) / 256, 256, 0, stream>>>(onehot, ohbf, send, recv,
                                                         cnt, elist2, E);
        fused2_k<0><<<NN / 2, 256, 0, stream>>>(onehot, ohbf, x, elist2, cnt,
                                                out_oh, out_x2,
                                                cw1, cb1, cw2, cb2, Wr, br, W1, b1);
    }
    bnpart_k<<<32, 256, 0, stream>>>(out_x2, part);
    out_k<<<NN / 16, 256, 0, stream>>>(out_x2, part, gamma, beta, W2, b2);
}

// Round 15
// 79.310 us; speedup vs baseline: 1.1826x; 1.1826x over previous
//
#include <hip/hip_runtime.h>
#include <hip/hip_bf16.h>
#include <math.h>

// Problem constants (fixed by the reference): N=2048 nodes, E=32768 edges,
// C_IN=C_OUT=128, OH_CH=8, onehot row length L=2048.
#define NN   2048
#define LROW 2048
#define DEGCAP 128   // max senders per receiver (Poisson(16); cap is ~8 sigma out)

typedef __attribute__((ext_vector_type(8))) short short8;
typedef __attribute__((ext_vector_type(4))) float f32x4;
typedef unsigned int u32;

__device__ __forceinline__ unsigned short bf16b(float x) {
    __hip_bfloat16 h = __float2bfloat16(x);
    return *reinterpret_cast<unsigned short*>(&h);
}

// ---- packed fp16 helpers (raw u32 regs + VOP3P asm; avoids fp16/bf16 header clash)

__device__ __forceinline__ u32 pkmin(u32 a, u32 b) {
    u32 d; asm("v_pk_min_f16 %0, %1, %2" : "=v"(d) : "v"(a), "v"(b)); return d;
}
__device__ __forceinline__ u32 pkmax(u32 a, u32 b) {
    u32 d; asm("v_pk_max_f16 %0, %1, %2" : "=v"(d) : "v"(a), "v"(b)); return d;
}
__device__ __forceinline__ u32 packf2(float lo, float hi) {
    union { _Float16 h[2]; u32 u; } c;
    c.h[0] = (_Float16)lo; c.h[1] = (_Float16)hi;
    return c.u;
}
__device__ __forceinline__ float unpk_lo(u32 v) {
    union { u32 u; _Float16 h[2]; } c; c.u = v; return (float)c.h[0];
}
__device__ __forceinline__ float unpk_hi(u32 v) {
    union { u32 u; _Float16 h[2]; } c; c.u = v; return (float)c.h[1];
}

// ---- lane-XOR exchange: DPP (VALU pipe, ~2cy) for D=1,2,8; ds_swizzle otherwise.
// quad_perm [1,0,3,2]=0xB1 is xor1; [2,3,0,1]=0x4E is xor2; row_ror:8=0x128 is
// xor8 within each 16-lane row. D is compile-time constant after full unroll,
// so dead branches fold away.
__device__ __forceinline__ u32 lanexor(u32 v, int D) {
    if (D == 1)  return (u32)__builtin_amdgcn_mov_dpp((int)v, 0xB1,  0xF, 0xF, true);
    if (D == 2)  return (u32)__builtin_amdgcn_mov_dpp((int)v, 0x4E,  0xF, 0xF, true);
    if (D == 8)  return (u32)__builtin_amdgcn_mov_dpp((int)v, 0x128, 0xF, 0xF, true);
    return (u32)__shfl_xor((int)v, D, 64);
}

// ---------------- prep: onehot f32->bf16 (rows) + adjacency fill (tail blocks) ----

__global__ __launch_bounds__(256) void prep_k(
        const float* __restrict__ oh, unsigned short* __restrict__ ohbf,
        const int* __restrict__ send, const int* __restrict__ recv,
        int* __restrict__ cnt, int* __restrict__ elist2, int E) {
    const int bid = blockIdx.x;
    if (bid < NN) {
        int base = bid * 2048 + threadIdx.x * 8;
        float4 f0 = *(const float4*)(oh + base);
        float4 f1 = *(const float4*)(oh + base + 4);
        union { short8 s8; unsigned short us[8]; } pk;
        pk.us[0] = bf16b(f0.x); pk.us[1] = bf16b(f0.y);
        pk.us[2] = bf16b(f0.z); pk.us[3] = bf16b(f0.w);
        pk.us[4] = bf16b(f1.x); pk.us[5] = bf16b(f1.y);
        pk.us[6] = bf16b(f1.z); pk.us[7] = bf16b(f1.w);
        *(short8*)(ohbf + base) = pk.s8;
    } else {
        int i = (bid - NN) * 256 + threadIdx.x;
        if (i < E) {
            int r = recv[i];
            int slot = atomicAdd(&cnt[r], 1);
            if (slot < DEGCAP) elist2[r * DEGCAP + slot] = send[i];
        }
    }
}

// ---------------- bitonic helpers ----------------

__device__ __forceinline__ void ce(float& a, float& b, bool up) {
    float lo = fminf(a, b), hi = fmaxf(a, b);
    a = up ? lo : hi;
    b = up ? hi : lo;
}

// merge a bitonic 8-seq held as 4 packed-fp16 u32 regs (dir uniform per thread)
__device__ __forceinline__ void ce_pk(u32& a, u32& b, bool up) {
    u32 mn = pkmin(a, b), mx = pkmax(a, b);
    a = up ? mn : mx;
    b = up ? mx : mn;
}

__device__ __forceinline__ void merge8_pk(u32 h[4], bool up) {
    ce_pk(h[0], h[2], up); ce_pk(h[1], h[3], up);   // j=4
    ce_pk(h[0], h[1], up); ce_pk(h[2], h[3], up);   // j=2
#pragma unroll
    for (int m = 0; m < 4; ++m) {                    // j=1 within reg
        u32 hs = (h[m] >> 16) | (h[m] << 16);
        u32 mn = pkmin(h[m], hs);                    // both lanes = min
        u32 mx = pkmax(h[m], hs);                    // both lanes = max
        u32 ru = __builtin_amdgcn_perm(mx, mn, 0x07060100u); // [mn.lo, mx.hi] asc
        u32 rd = __builtin_amdgcn_perm(mn, mx, 0x07060100u); // [mx.lo, mn.hi] desc
        h[m] = up ? ru : rd;
    }
}

__device__ __forceinline__ short8 conv1pack(float xm, float x0v, float xp,
        const float* __restrict__ cw1, const float* __restrict__ cb1) {
    union { short8 s8; unsigned short us[8]; } pk;
#pragma unroll
    for (int c = 0; c < 8; ++c) {
        float w = cb1[c] + cw1[c * 3] * xm + cw1[c * 3 + 1] * x0v + cw1[c * 3 + 2] * xp;
        pk.us[c] = bf16b(w > 0.f ? w : 0.f);
    }
    return pk.s8;
}

// ---------------- fused: gather + packed-fp16 sort (DPP) + conv(MFMA) + lin1 ----
// launch_bounds(256,6): VGPR ~40 natural (R12), no spill. (256,8) and 2-row ILP
// both re-introduced spill (R13/R14) -- this block shape is the local optimum.

template<int BF>
__global__ __launch_bounds__(256, 6) void fused_k(
        const float* __restrict__ oh, const unsigned short* __restrict__ ohbf,
        const float* __restrict__ x,
        const int* __restrict__ elist2, const int* __restrict__ cnt,
        float* __restrict__ newoh, float* __restrict__ t,
        const float* __restrict__ cw1, const float* __restrict__ cb1,
        const float* __restrict__ cw2, const float* __restrict__ cb2,
        const float* __restrict__ Wr,  const float* __restrict__ br,
        const float* __restrict__ W1,  const float* __restrict__ b1) {
    // time-shared: sort staging (u32 or f32), then [1028][8] bf16 h1t (16448 B)
    __shared__ __align__(16) char smem[1028 * 16];
    float* sf = (float*)smem;
    u32* sfu = (u32*)smem;
    unsigned short* h1t = (unsigned short*)smem;
    __shared__ unsigned short a_lds[16 * 32];
    __shared__ float red[4][16];
    __shared__ float u[136];
    __shared__ float lpart[128];

    const int r = blockIdx.x, tid = threadIdx.x;
    const int lane = tid & 63, wv = tid >> 6;
    const int col = tid * 8;

    // ---- build bf16 A tile: [16 c2][32 k], k = 8*d + c1 ----
    for (int i = tid; i < 512; i += 256) {
        int c2 = i >> 5, k = i & 31, d = k >> 3, c1 = k & 7;
        float w = (d < 3) ? cw2[(c2 * 8 + c1) * 3 + d] : 0.f;
        a_lds[i] = bf16b(w);
    }

    // ---- gather: v[8] = onehot[r][col..col+7] + sum over senders; myagg ----
    float v[8];
    {
        float4 b0 = *(const float4*)(oh + (size_t)r * LROW + col);
        float4 b1v = *(const float4*)(oh + (size_t)r * LROW + col + 4);
        v[0] = b0.x;  v[1] = b0.y;  v[2] = b0.z;  v[3] = b0.w;
        v[4] = b1v.x; v[5] = b1v.y; v[6] = b1v.z; v[7] = b1v.w;
    }
    float myagg = 0.f;
    const int deg = min(cnt[r], DEGCAP);
    const int* my = elist2 + r * DEGCAP;
    int e = 0;
    if (BF) {
        for (; e + 4 <= deg; e += 4) {
            int se0 = my[e], se1 = my[e + 1], se2 = my[e + 2], se3 = my[e + 3];
            uint4 ua = *((const uint4*)(ohbf + (size_t)se0 * LROW) + tid);
            uint4 ub = *((const uint4*)(ohbf + (size_t)se1 * LROW) + tid);
            uint4 uc = *((const uint4*)(ohbf + (size_t)se2 * LROW) + tid);
            uint4 ud = *((const uint4*)(ohbf + (size_t)se3 * LROW) + tid);
            float xa = 0.f, xb = 0.f, xc = 0.f, xd = 0.f;
            if (tid < 128) {
                xa = x[(size_t)se0 * 128 + tid]; xb = x[(size_t)se1 * 128 + tid];
                xc = x[(size_t)se2 * 128 + tid]; xd = x[(size_t)se3 * 128 + tid];
            }
            v[0] += __uint_as_float(ua.x << 16); v[1] += __uint_as_float(ua.x & 0xffff0000u);
            v[2] += __uint_as_float(ua.y << 16); v[3] += __uint_as_float(ua.y & 0xffff0000u);
            v[4] += __uint_as_float(ua.z << 16); v[5] += __uint_as_float(ua.z & 0xffff0000u);
            v[6] += __uint_as_float(ua.w << 16); v[7] += __uint_as_float(ua.w & 0xffff0000u);
            v[0] += __uint_as_float(ub.x << 16); v[1] += __uint_as_float(ub.x & 0xffff0000u);
            v[2] += __uint_as_float(ub.y << 16); v[3] += __uint_as_float(ub.y & 0xffff0000u);
            v[4] += __uint_as_float(ub.z << 16); v[5] += __uint_as_float(ub.z & 0xffff0000u);
            v[6] += __uint_as_float(ub.w << 16); v[7] += __uint_as_float(ub.w & 0xffff0000u);
            v[0] += __uint_as_float(uc.x << 16); v[1] += __uint_as_float(uc.x & 0xffff0000u);
            v[2] += __uint_as_float(uc.y << 16); v[3] += __uint_as_float(uc.y & 0xffff0000u);
            v[4] += __uint_as_float(uc.z << 16); v[5] += __uint_as_float(uc.z & 0xffff0000u);
            v[6] += __uint_as_float(uc.w << 16); v[7] += __uint_as_float(uc.w & 0xffff0000u);
            v[0] += __uint_as_float(ud.x << 16); v[1] += __uint_as_float(ud.x & 0xffff0000u);
            v[2] += __uint_as_float(ud.y << 16); v[3] += __uint_as_float(ud.y & 0xffff0000u);
            v[4] += __uint_as_float(ud.z << 16); v[5] += __uint_as_float(ud.z & 0xffff0000u);
            v[6] += __uint_as_float(ud.w << 16); v[7] += __uint_as_float(ud.w & 0xffff0000u);
            myagg += xa; myagg += xb; myagg += xc; myagg += xd;
        }
        for (; e < deg; ++e) {
            int se = my[e];
            uint4 ua = *((const uint4*)(ohbf + (size_t)se * LROW) + tid);
            if (tid < 128) myagg += x[(size_t)se * 128 + tid];
            v[0] += __uint_as_float(ua.x << 16); v[1] += __uint_as_float(ua.x & 0xffff0000u);
            v[2] += __uint_as_float(ua.y << 16); v[3] += __uint_as_float(ua.y & 0xffff0000u);
            v[4] += __uint_as_float(ua.z << 16); v[5] += __uint_as_float(ua.z & 0xffff0000u);
            v[6] += __uint_as_float(ua.w << 16); v[7] += __uint_as_float(ua.w & 0xffff0000u);
        }
    } else {
        for (; e + 2 <= deg; e += 2) {
            int se0 = my[e], se1 = my[e + 1];
            float4 c0 = *(const float4*)(oh + (size_t)se0 * LROW + col);
            float4 c1 = *(const float4*)(oh + (size_t)se0 * LROW + col + 4);
            float4 d0 = *(const float4*)(oh + (size_t)se1 * LROW + col);
            float4 d1 = *(const float4*)(oh + (size_t)se1 * LROW + col + 4);
            float xa = 0.f, xb = 0.f;
            if (tid < 128) { xa = x[(size_t)se0 * 128 + tid]; xb = x[(size_t)se1 * 128 + tid]; }
            v[0] += c0.x; v[1] += c0.y; v[2] += c0.z; v[3] += c0.w;
            v[4] += c1.x; v[5] += c1.y; v[6] += c1.z; v[7] += c1.w;
            v[0] += d0.x; v[1] += d0.y; v[2] += d0.z; v[3] += d0.w;
            v[4] += d1.x; v[5] += d1.y; v[6] += d1.z; v[7] += d1.w;
            myagg += xa; myagg += xb;
        }
        for (; e < deg; ++e) {
            int se = my[e];
            float4 c0 = *(const float4*)(oh + (size_t)se * LROW + col);
            float4 c1 = *(const float4*)(oh + (size_t)se * LROW + col + 4);
            if (tid < 128) myagg += x[(size_t)se * 128 + tid];
            v[0] += c0.x; v[1] += c0.y; v[2] += c0.z; v[3] += c0.w;
            v[4] += c1.x; v[5] += c1.y; v[6] += c1.z; v[7] += c1.w;
        }
    }
    // write new_oh (output) straight from the exact f32 accumulators
    *(float4*)(newoh + (size_t)r * LROW + col)     = make_float4(v[0], v[1], v[2], v[3]);
    *(float4*)(newoh + (size_t)r * LROW + col + 4) = make_float4(v[4], v[5], v[6], v[7]);

    // ---- bitonic sort: k=2..8 in f32 registers ----
    ce(v[0], v[1], true);  ce(v[2], v[3], false); ce(v[4], v[5], true);  ce(v[6], v[7], false);
    ce(v[0], v[2], true);  ce(v[1], v[3], true);  ce(v[4], v[6], false); ce(v[5], v[7], false);
    ce(v[0], v[1], true);  ce(v[2], v[3], true);  ce(v[4], v[5], false); ce(v[6], v[7], false);
    {
        bool up8 = (tid & 1) == 0;
        ce(v[0], v[4], up8); ce(v[1], v[5], up8); ce(v[2], v[6], up8); ce(v[3], v[7], up8);
        ce(v[0], v[2], up8); ce(v[1], v[3], up8); ce(v[4], v[6], up8); ce(v[5], v[7], up8);
        ce(v[0], v[1], up8); ce(v[2], v[3], up8); ce(v[4], v[5], up8); ce(v[6], v[7], up8);
    }

    // ---- pack to fp16 (monotone rounding keeps bitonic invariants);
    //      k=16..2048 packed; cross-lane via DPP (D=1,2,8) or ds_swizzle ----
    u32 h[4];
    h[0] = packf2(v[0], v[1]);
    h[1] = packf2(v[2], v[3]);
    h[2] = packf2(v[4], v[5]);
    h[3] = packf2(v[6], v[7]);

#pragma unroll
    for (int lk = 4; lk <= 11; ++lk) {
        const int k = 1 << lk;
        const bool up = ((tid & (k >> 3)) == 0);
#pragma unroll
        for (int lj = lk - 1; lj >= 3; --lj) {
            const int D = 1 << (lj - 3);
            const bool keepmin = (((tid & D) == 0) == up);
            if (D <= 32) {
#pragma unroll
                for (int m = 0; m < 4; ++m) {
                    u32 hs = lanexor(h[m], D);
                    u32 mn = pkmin(h[m], hs), mx = pkmax(h[m], hs);
                    h[m] = keepmin ? mn : mx;
                }
            } else {
                __syncthreads();
                *(uint4*)&sfu[tid * 4] = make_uint4(h[0], h[1], h[2], h[3]);
                __syncthreads();
                uint4 P = *(const uint4*)&sfu[(tid ^ D) * 4];
                h[0] = keepmin ? pkmin(h[0], P.x) : pkmax(h[0], P.x);
                h[1] = keepmin ? pkmin(h[1], P.y) : pkmax(h[1], P.y);
                h[2] = keepmin ? pkmin(h[2], P.z) : pkmax(h[2], P.z);
                h[3] = keepmin ? pkmin(h[3], P.w) : pkmax(h[3], P.w);
            }
        }
        merge8_pk(h, up);
    }

    // ---- unpack sorted values to f32 ----
    v[0] = unpk_lo(h[0]); v[1] = unpk_hi(h[0]);
    v[2] = unpk_lo(h[1]); v[3] = unpk_hi(h[1]);
    v[4] = unpk_lo(h[2]); v[5] = unpk_hi(h[2]);
    v[6] = unpk_lo(h[3]); v[7] = unpk_hi(h[3]);

    // ---- stage sorted row; fetch chunk-edge neighbors ----
    __syncthreads();
    *(float4*)&sf[col]     = make_float4(v[0], v[1], v[2], v[3]);
    *(float4*)&sf[col + 4] = make_float4(v[4], v[5], v[6], v[7]);
    __syncthreads();
    float lf1 = (tid == 0)   ? 0.f : sf[col - 1];
    float rt1 = (tid == 255) ? 0.f : sf[col + 8];

    // ---- two half-row phases: conv1 -> h1t (bf16, swizzled) -> MFMA ----
    short8 afrag = *(const short8*)&a_lds[(lane & 15) * 32 + (lane >> 4) * 8];
    const int mb = (lane >> 4) * 4;
    const float bs0 = cb2[mb], bs1 = cb2[mb + 1], bs2 = cb2[mb + 2], bs3 = cb2[mb + 3];
    float s0 = 0.f, s1 = 0.f, s2 = 0.f, s3 = 0.f;
    f32x4 zero = {0.f, 0.f, 0.f, 0.f};

#pragma unroll 1
    for (int half = 0; half < 2; ++half) {
        __syncthreads();   // previous phase's LDS reads (sf or MFMA) complete
        if ((tid >> 7) == half) {
            const int lt = tid & 127;
#pragma unroll
            for (int p = 0; p < 8; ++p) {
                float xm  = (p == 0) ? lf1 : v[p - 1];
                float x0v = v[p];
                float xp  = (p == 7) ? rt1 : v[p + 1];
                int uu = lt * 8 + p + 1;
                int us = uu ^ ((uu >> 3) & 7);
                *(short8*)&h1t[us * 8] = conv1pack(xm, x0v, xp, cw1, cb1);
            }
        }
        if (half == 0) {
            if (tid == 128)   // h1[1024] (slot 1025): xm=s[1023]=lf1
                *(short8*)&h1t[1025 * 8] = conv1pack(lf1, v[0], v[1], cw1, cb1);
            if (tid == 0) {   // h1[-1] = 0
                short8 z = {0, 0, 0, 0, 0, 0, 0, 0};
                *(short8*)&h1t[0] = z;
            }
            if (tid == 1) {   // d=3 overreach slots: must be finite (A row is 0)
                short8 z = {0, 0, 0, 0, 0, 0, 0, 0};
                *(short8*)&h1t[1026 * 8] = z;
                *(short8*)&h1t[1027 * 8] = z;
            }
        } else {
            if (tid == 127)   // h1[1023] (slot 0): xp=s[1024]=rt1
                *(short8*)&h1t[0] = conv1pack(v[6], v[7], rt1, cw1, cb1);
            if (tid == 0) {   // h1[2048] = 0
                short8 z = {0, 0, 0, 0, 0, 0, 0, 0};
                *(short8*)&h1t[1025 * 8] = z;
            }
        }
        __syncthreads();

#pragma unroll 4
        for (int i = 0; i < 16; ++i) {
            int lp = (wv * 16 + i) * 16 + (lane & 15);   // local position 0..1023
            int uu = lp + (lane >> 4);                   // slot = local_pos + d
            int us = uu ^ ((uu >> 3) & 7);
            short8 bfrag = *(const short8*)&h1t[us * 8];
            f32x4 d = __builtin_amdgcn_mfma_f32_16x16x32_bf16(afrag, bfrag, zero, 0, 0, 0);
            s0 += fmaxf(d[0] + bs0, 0.f);
            s1 += fmaxf(d[1] + bs1, 0.f);
            s2 += fmaxf(d[2] + bs2, 0.f);
            s3 += fmaxf(d[3] + bs3, 0.f);
        }
    }

    // ---- reduce over the 16 column-lanes (positions) ----
#pragma unroll
    for (int off = 1; off < 16; off <<= 1) {
        s0 += __shfl_xor(s0, off);
        s1 += __shfl_xor(s1, off);
        s2 += __shfl_xor(s2, off);
        s3 += __shfl_xor(s3, off);
    }
    if ((lane & 15) == 0) {
        red[wv][mb + 0] = s0; red[wv][mb + 1] = s1;
        red[wv][mb + 2] = s2; red[wv][mb + 3] = s3;
    }
    if (tid < 128) u[tid] = myagg;
    __syncthreads();

    // ---- readout = mean @ Wr + br ----
    if (tid < 8) {
        float acc = br[tid];
#pragma unroll
        for (int c = 0; c < 16; ++c) {
            float tot = red[0][c] + red[1][c] + red[2][c] + red[3][c];
            acc += (tot * (1.0f / (float)LROW)) * Wr[c * 8 + tid];
        }
        u[128 + tid] = acc;
    }
    __syncthreads();

    // ---- lin1: t[r] = concat(aggx, readout) @ W1 + b1 ----
    {
        const int jc = tid & 127, hf = tid >> 7;
        float acc = (hf == 0) ? b1[jc] : 0.f;
        const int c0 = hf * 68;
#pragma unroll 4
        for (int c = 0; c < 68; ++c) acc += u[c0 + c] * W1[(size_t)(c0 + c) * 128 + jc];
        if (hf) lpart[jc] = acc;
        __syncthreads();
        if (!hf) t[(size_t)r * 128 + jc] = acc + lpart[jc];
    }
}

// ---------------- BN stats stage 1, coalesced, deterministic ----------------

__global__ __launch_bounds__(256) void bnpart_k(const float* __restrict__ t,
                                                float* __restrict__ part) {
    const int b = blockIdx.x, tid = threadIdx.x;
    const int col = tid & 127, h = tid >> 7;
    float sm = 0.f, sq = 0.f;
    for (int i = 0; i < 32; ++i) {
        int row = b * 64 + h * 32 + i;
        float v = t[(size_t)row * 128 + col];
        sm += v; sq += v * v;
    }
    __shared__ float ps[2][128], pq[2][128];
    ps[h][col] = sm; pq[h][col] = sq;
    __syncthreads();
    if (h == 0) {
        part[(size_t)b * 256 + col]       = sm + ps[1][col];
        part[(size_t)b * 256 + 128 + col] = sq + pq[1][col];
    }
}

// ---------------- BN finalize (inline) + ReLU + @W2 + b2, 16 rows/block ----------

__global__ __launch_bounds__(256) void out_k(
        float* __restrict__ t, const float* __restrict__ part,
        const float* __restrict__ gamma, const float* __restrict__ beta,
        const float* __restrict__ W2, const float* __restrict__ b2) {
    __shared__ float u[16][128];
    __shared__ float sc_s[128], sh_s[128];
    const int r0 = blockIdx.x * 16, tid = threadIdx.x;
    if (tid < 128) {
        float sm = 0.f, sq = 0.f;
        for (int b = 0; b < 32; ++b) {
            sm += part[(size_t)b * 256 + tid];
            sq += part[(size_t)b * 256 + 128 + tid];
        }
        float mu  = sm / (float)NN;
        float var = sq / (float)NN - mu * mu;
        float sc  = rsqrtf(var + 1e-5f) * gamma[tid];
        sc_s[tid] = sc;
        sh_s[tid] = beta[tid] - mu * sc;
    }
    __syncthreads();
#pragma unroll
    for (int m = 0; m < 8; ++m) {
        int idx = tid + 256 * m;
        int rr = idx >> 7, c = idx & 127;
        float v = t[(size_t)(r0 + rr) * 128 + c];
        v = v * sc_s[c] + sh_s[c];
        u[rr][c] = v > 0.f ? v : 0.f;
    }
    __syncthreads();
    const int j = tid & 127, g = tid >> 7;
    float acc[8];
    float bb = b2[j];
#pragma unroll
    for (int rr = 0; rr < 8; ++rr) acc[rr] = bb;
    for (int c = 0; c < 128; ++c) {
        float w = W2[(size_t)c * 128 + j];
#pragma unroll
        for (int rr = 0; rr < 8; ++rr) acc[rr] += u[g * 8 + rr][c] * w;
    }
#pragma unroll
    for (int rr = 0; rr < 8; ++rr)
        t[(size_t)(r0 + g * 8 + rr) * 128 + j] = acc[rr];
}

// ---------------- launch ----------------

extern "C" void kernel_launch(void* const* d_in, const int* in_sizes, int n_in,
                              void* d_out, int out_size, void* d_ws, size_t ws_size,
                              hipStream_t stream) {
    const float* x      = (const float*)d_in[0];
    const float* onehot = (const float*)d_in[1];
    const int*   adj    = (const int*)d_in[2];
    // d_in[3] = n_nodes (scalar), fixed at 2048
    const float* W1     = (const float*)d_in[4];
    const float* b1     = (const float*)d_in[5];
    const float* gamma  = (const float*)d_in[6];
    const float* beta   = (const float*)d_in[7];
    const float* W2     = (const float*)d_in[8];
    const float* b2     = (const float*)d_in[9];
    const float* cw1    = (const float*)d_in[10];
    const float* cb1    = (const float*)d_in[11];
    const float* cw2    = (const float*)d_in[12];
    const float* cb2    = (const float*)d_in[13];
    const float* Wr     = (const float*)d_in[14];
    const float* br     = (const float*)d_in[15];

    const int E = in_sizes[2] / 2;
    const int* send = adj;
    const int* recv = adj + E;

    // workspace layout
    int*   cnt    = (int*)d_ws;                          // 2048 ints
    int*   elist2 = cnt + 2048;                          // 2048*DEGCAP ints
    float* part   = (float*)(elist2 + NN * DEGCAP);      // 32*256
    unsigned short* ohbf = (unsigned short*)(part + 32 * 256);  // 2048*2048 bf16
    size_t need = (size_t)((char*)(ohbf + (size_t)NN * LROW) - (char*)d_ws);
    const bool bf_path = (ws_size >= need);

    float* out_x2 = (float*)d_out;              // [2048,128] (staged pre-BN, then final)
    float* out_oh = out_x2 + (size_t)NN * 128;  // [2048,2048]

    hipMemsetAsync(cnt, 0, 2048 * sizeof(int), stream);

    if (bf_path) {
        prep_k<<<NN + (E + 255) / 256, 256, 0, stream>>>(onehot, ohbf, send, recv,
                                                         cnt, elist2, E);
        fused_k<1><<<NN, 256, 0, stream>>>(onehot, ohbf, x, elist2, cnt,
                                           out_oh, out_x2,
                                           cw1, cb1, cw2, cb2, Wr, br, W1, b1);
    } else {
        prep_k<<<NN + (E + 255) / 256, 256, 0, stream>>>(onehot, ohbf, send, recv,
                                                         cnt, elist2, E);
        fused_k<0><<<NN, 256, 0, stream>>>(onehot, ohbf, x, elist2, cnt,
                                           out_oh, out_x2,
                                           cw1, cb1, cw2, cb2, Wr, br, W1, b1);
    }
    bnpart_k<<<32, 256, 0, stream>>>(out_x2, part);
    out_k<<<NN / 16, 256, 0, stream>>>(out_x2, part, gamma, beta, W2, b2);
}

// Round 16
// 79.238 us; speedup vs baseline: 1.1837x; 1.0009x over previous
//
#include <hip/hip_runtime.h>
#include <hip/hip_bf16.h>
#include <math.h>

// Problem constants (fixed by the reference): N=2048 nodes, E=32768 edges,
// C_IN=C_OUT=128, OH_CH=8, onehot row length L=2048.
#define NN   2048
#define LROW 2048
#define DEGCAP 128   // max senders per receiver (Poisson(16); cap is ~8 sigma out)

typedef __attribute__((ext_vector_type(8))) short short8;
typedef __attribute__((ext_vector_type(4))) float f32x4;
typedef unsigned int u32;

__device__ __forceinline__ unsigned short bf16b(float x) {
    __hip_bfloat16 h = __float2bfloat16(x);
    return *reinterpret_cast<unsigned short*>(&h);
}

// ---- packed fp16 helpers (raw u32 regs + VOP3P asm; avoids fp16/bf16 header clash)

__device__ __forceinline__ u32 pkmin(u32 a, u32 b) {
    u32 d; asm("v_pk_min_f16 %0, %1, %2" : "=v"(d) : "v"(a), "v"(b)); return d;
}
__device__ __forceinline__ u32 pkmax(u32 a, u32 b) {
    u32 d; asm("v_pk_max_f16 %0, %1, %2" : "=v"(d) : "v"(a), "v"(b)); return d;
}
__device__ __forceinline__ u32 packf2(float lo, float hi) {
    union { _Float16 h[2]; u32 u; } c;
    c.h[0] = (_Float16)lo; c.h[1] = (_Float16)hi;
    return c.u;
}
__device__ __forceinline__ float unpk_lo(u32 v) {
    union { u32 u; _Float16 h[2]; } c; c.u = v; return (float)c.h[0];
}
__device__ __forceinline__ float unpk_hi(u32 v) {
    union { u32 u; _Float16 h[2]; } c; c.u = v; return (float)c.h[1];
}

// ---- lane-XOR exchange:
//  D=1,2  : quad_perm DPP (VALU, ~2cy)
//  D=8    : row_ror:8 DPP (xor8 within 16-lane row)
//  D=32   : v_permlane32_swap_b32 (VALU; r0 valid for lane<32, r1 for lane>=32)
//  D=4,16 : ds_swizzle via __shfl_xor (cross-quad / cross-row, no DPP form)
__device__ __forceinline__ u32 lanexor(u32 v, int D, bool lo32) {
    if (D == 1)  return (u32)__builtin_amdgcn_mov_dpp((int)v, 0xB1,  0xF, 0xF, true);
    if (D == 2)  return (u32)__builtin_amdgcn_mov_dpp((int)v, 0x4E,  0xF, 0xF, true);
    if (D == 8)  return (u32)__builtin_amdgcn_mov_dpp((int)v, 0x128, 0xF, 0xF, true);
    if (D == 32) {
        u32 a = v, b = v;
        asm("v_permlane32_swap_b32 %0, %1" : "+v"(a), "+v"(b));
        return lo32 ? a : b;   // lane<32: a = v[lane+32]; lane>=32: b = v[lane-32]
    }
    return (u32)__shfl_xor((int)v, D, 64);
}

// ---------------- prep: onehot f32->bf16 (rows) + adjacency fill (tail blocks) ----

__global__ __launch_bounds__(256) void prep_k(
        const float* __restrict__ oh, unsigned short* __restrict__ ohbf,
        const int* __restrict__ send, const int* __restrict__ recv,
        int* __restrict__ cnt, int* __restrict__ elist2, int E) {
    const int bid = blockIdx.x;
    if (bid < NN) {
        int base = bid * 2048 + threadIdx.x * 8;
        float4 f0 = *(const float4*)(oh + base);
        float4 f1 = *(const float4*)(oh + base + 4);
        union { short8 s8; unsigned short us[8]; } pk;
        pk.us[0] = bf16b(f0.x); pk.us[1] = bf16b(f0.y);
        pk.us[2] = bf16b(f0.z); pk.us[3] = bf16b(f0.w);
        pk.us[4] = bf16b(f1.x); pk.us[5] = bf16b(f1.y);
        pk.us[6] = bf16b(f1.z); pk.us[7] = bf16b(f1.w);
        *(short8*)(ohbf + base) = pk.s8;
    } else {
        int i = (bid - NN) * 256 + threadIdx.x;
        if (i < E) {
            int r = recv[i];
            int slot = atomicAdd(&cnt[r], 1);
            if (slot < DEGCAP) elist2[r * DEGCAP + slot] = send[i];
        }
    }
}

// ---------------- bitonic helpers ----------------

__device__ __forceinline__ void ce(float& a, float& b, bool up) {
    float lo = fminf(a, b), hi = fmaxf(a, b);
    a = up ? lo : hi;
    b = up ? hi : lo;
}

__device__ __forceinline__ void ce_pk(u32& a, u32& b, bool up) {
    u32 mn = pkmin(a, b), mx = pkmax(a, b);
    a = up ? mn : mx;
    b = up ? mx : mn;
}

// merge a bitonic 8-seq held as 4 packed-fp16 u32 regs (dir uniform per thread)
__device__ __forceinline__ void merge8_pk(u32 h[4], bool up) {
    ce_pk(h[0], h[2], up); ce_pk(h[1], h[3], up);   // j=4
    ce_pk(h[0], h[1], up); ce_pk(h[2], h[3], up);   // j=2
#pragma unroll
    for (int m = 0; m < 4; ++m) {                    // j=1 within reg
        u32 hs = (h[m] >> 16) | (h[m] << 16);
        u32 mn = pkmin(h[m], hs);                    // both lanes = min
        u32 mx = pkmax(h[m], hs);                    // both lanes = max
        u32 ru = __builtin_amdgcn_perm(mx, mn, 0x07060100u); // [mn.lo, mx.hi] asc
        u32 rd = __builtin_amdgcn_perm(mn, mx, 0x07060100u); // [mx.lo, mn.hi] desc
        h[m] = up ? ru : rd;
    }
}

__device__ __forceinline__ short8 conv1pack(float xm, float x0v, float xp,
        const float* __restrict__ cw1, const float* __restrict__ cb1) {
    union { short8 s8; unsigned short us[8]; } pk;
#pragma unroll
    for (int c = 0; c < 8; ++c) {
        float w = cb1[c] + cw1[c * 3] * xm + cw1[c * 3 + 1] * x0v + cw1[c * 3 + 2] * xp;
        pk.us[c] = bf16b(w > 0.f ? w : 0.f);
    }
    return pk.s8;
}

// ---------------- fused: gather + packed-fp16 sort (DPP/permlane) + conv(MFMA)
//                  + lin1. (256,6): VGPR ~40 natural, no spill (R12/R15). ----

template<int BF>
__global__ __launch_bounds__(256, 6) void fused_k(
        const float* __restrict__ oh, const unsigned short* __restrict__ ohbf,
        const float* __restrict__ x,
        const int* __restrict__ elist2, const int* __restrict__ cnt,
        float* __restrict__ newoh, float* __restrict__ t,
        const float* __restrict__ cw1, const float* __restrict__ cb1,
        const float* __restrict__ cw2, const float* __restrict__ cb2,
        const float* __restrict__ Wr,  const float* __restrict__ br,
        const float* __restrict__ W1,  const float* __restrict__ b1) {
    // time-shared: sort staging (u32), then [1028][8] bf16 h1t (16448 B)
    __shared__ __align__(16) char smem[1028 * 16];
    u32* sfu = (u32*)smem;
    unsigned short* h1t = (unsigned short*)smem;
    __shared__ unsigned short a_lds[16 * 32];
    __shared__ float red[4][16];
    __shared__ float u[136];
    __shared__ float lpart[128];
    __shared__ float edgeA[4], edgeB[4];   // wave-boundary v[7] / v[0]

    const int r = blockIdx.x, tid = threadIdx.x;
    const int lane = tid & 63, wv = tid >> 6;
    const int col = tid * 8;
    const bool lo32 = (lane < 32);

    // ---- build bf16 A tile: [16 c2][32 k], k = 8*d + c1 ----
    for (int i = tid; i < 512; i += 256) {
        int c2 = i >> 5, k = i & 31, d = k >> 3, c1 = k & 7;
        float w = (d < 3) ? cw2[(c2 * 8 + c1) * 3 + d] : 0.f;
        a_lds[i] = bf16b(w);
    }

    // ---- gather: v[8] = onehot[r][col..col+7] + sum over senders; myagg ----
    float v[8];
    {
        float4 b0 = *(const float4*)(oh + (size_t)r * LROW + col);
        float4 b1v = *(const float4*)(oh + (size_t)r * LROW + col + 4);
        v[0] = b0.x;  v[1] = b0.y;  v[2] = b0.z;  v[3] = b0.w;
        v[4] = b1v.x; v[5] = b1v.y; v[6] = b1v.z; v[7] = b1v.w;
    }
    float myagg = 0.f;
    const int deg = min(cnt[r], DEGCAP);
    const int* my = elist2 + r * DEGCAP;
    int e = 0;
    if (BF) {
        for (; e + 4 <= deg; e += 4) {
            int se0 = my[e], se1 = my[e + 1], se2 = my[e + 2], se3 = my[e + 3];
            uint4 ua = *((const uint4*)(ohbf + (size_t)se0 * LROW) + tid);
            uint4 ub = *((const uint4*)(ohbf + (size_t)se1 * LROW) + tid);
            uint4 uc = *((const uint4*)(ohbf + (size_t)se2 * LROW) + tid);
            uint4 ud = *((const uint4*)(ohbf + (size_t)se3 * LROW) + tid);
            float xa = 0.f, xb = 0.f, xc = 0.f, xd = 0.f;
            if (tid < 128) {
                xa = x[(size_t)se0 * 128 + tid]; xb = x[(size_t)se1 * 128 + tid];
                xc = x[(size_t)se2 * 128 + tid]; xd = x[(size_t)se3 * 128 + tid];
            }
            v[0] += __uint_as_float(ua.x << 16); v[1] += __uint_as_float(ua.x & 0xffff0000u);
            v[2] += __uint_as_float(ua.y << 16); v[3] += __uint_as_float(ua.y & 0xffff0000u);
            v[4] += __uint_as_float(ua.z << 16); v[5] += __uint_as_float(ua.z & 0xffff0000u);
            v[6] += __uint_as_float(ua.w << 16); v[7] += __uint_as_float(ua.w & 0xffff0000u);
            v[0] += __uint_as_float(ub.x << 16); v[1] += __uint_as_float(ub.x & 0xffff0000u);
            v[2] += __uint_as_float(ub.y << 16); v[3] += __uint_as_float(ub.y & 0xffff0000u);
            v[4] += __uint_as_float(ub.z << 16); v[5] += __uint_as_float(ub.z & 0xffff0000u);
            v[6] += __uint_as_float(ub.w << 16); v[7] += __uint_as_float(ub.w & 0xffff0000u);
            v[0] += __uint_as_float(uc.x << 16); v[1] += __uint_as_float(uc.x & 0xffff0000u);
            v[2] += __uint_as_float(uc.y << 16); v[3] += __uint_as_float(uc.y & 0xffff0000u);
            v[4] += __uint_as_float(uc.z << 16); v[5] += __uint_as_float(uc.z & 0xffff0000u);
            v[6] += __uint_as_float(uc.w << 16); v[7] += __uint_as_float(uc.w & 0xffff0000u);
            v[0] += __uint_as_float(ud.x << 16); v[1] += __uint_as_float(ud.x & 0xffff0000u);
            v[2] += __uint_as_float(ud.y << 16); v[3] += __uint_as_float(ud.y & 0xffff0000u);
            v[4] += __uint_as_float(ud.z << 16); v[5] += __uint_as_float(ud.z & 0xffff0000u);
            v[6] += __uint_as_float(ud.w << 16); v[7] += __uint_as_float(ud.w & 0xffff0000u);
            myagg += xa; myagg += xb; myagg += xc; myagg += xd;
        }
        for (; e < deg; ++e) {
            int se = my[e];
            uint4 ua = *((const uint4*)(ohbf + (size_t)se * LROW) + tid);
            if (tid < 128) myagg += x[(size_t)se * 128 + tid];
            v[0] += __uint_as_float(ua.x << 16); v[1] += __uint_as_float(ua.x & 0xffff0000u);
            v[2] += __uint_as_float(ua.y << 16); v[3] += __uint_as_float(ua.y & 0xffff0000u);
            v[4] += __uint_as_float(ua.z << 16); v[5] += __uint_as_float(ua.z & 0xffff0000u);
            v[6] += __uint_as_float(ua.w << 16); v[7] += __uint_as_float(ua.w & 0xffff0000u);
        }
    } else {
        for (; e + 2 <= deg; e += 2) {
            int se0 = my[e], se1 = my[e + 1];
            float4 c0 = *(const float4*)(oh + (size_t)se0 * LROW + col);
            float4 c1 = *(const float4*)(oh + (size_t)se0 * LROW + col + 4);
            float4 d0 = *(const float4*)(oh + (size_t)se1 * LROW + col);
            float4 d1 = *(const float4*)(oh + (size_t)se1 * LROW + col + 4);
            float xa = 0.f, xb = 0.f;
            if (tid < 128) { xa = x[(size_t)se0 * 128 + tid]; xb = x[(size_t)se1 * 128 + tid]; }
            v[0] += c0.x; v[1] += c0.y; v[2] += c0.z; v[3] += c0.w;
            v[4] += c1.x; v[5] += c1.y; v[6] += c1.z; v[7] += c1.w;
            v[0] += d0.x; v[1] += d0.y; v[2] += d0.z; v[3] += d0.w;
            v[4] += d1.x; v[5] += d1.y; v[6] += d1.z; v[7] += d1.w;
            myagg += xa; myagg += xb;
        }
        for (; e < deg; ++e) {
            int se = my[e];
            float4 c0 = *(const float4*)(oh + (size_t)se * LROW + col);
            float4 c1 = *(const float4*)(oh + (size_t)se * LROW + col + 4);
            if (tid < 128) myagg += x[(size_t)se * 128 + tid];
            v[0] += c0.x; v[1] += c0.y; v[2] += c0.z; v[3] += c0.w;
            v[4] += c1.x; v[5] += c1.y; v[6] += c1.z; v[7] += c1.w;
        }
    }
    // write new_oh (output) straight from the exact f32 accumulators
    *(float4*)(newoh + (size_t)r * LROW + col)     = make_float4(v[0], v[1], v[2], v[3]);
    *(float4*)(newoh + (size_t)r * LROW + col + 4) = make_float4(v[4], v[5], v[6], v[7]);

    // ---- bitonic sort: k=2..8 in f32 registers ----
    ce(v[0], v[1], true);  ce(v[2], v[3], false); ce(v[4], v[5], true);  ce(v[6], v[7], false);
    ce(v[0], v[2], true);  ce(v[1], v[3], true);  ce(v[4], v[6], false); ce(v[5], v[7], false);
    ce(v[0], v[1], true);  ce(v[2], v[3], true);  ce(v[4], v[5], false); ce(v[6], v[7], false);
    {
        bool up8 = (tid & 1) == 0;
        ce(v[0], v[4], up8); ce(v[1], v[5], up8); ce(v[2], v[6], up8); ce(v[3], v[7], up8);
        ce(v[0], v[2], up8); ce(v[1], v[3], up8); ce(v[4], v[6], up8); ce(v[5], v[7], up8);
        ce(v[0], v[1], up8); ce(v[2], v[3], up8); ce(v[4], v[5], up8); ce(v[6], v[7], up8);
    }

    // ---- pack to fp16 (monotone rounding keeps bitonic invariants);
    //      k=16..2048 packed; cross-lane via DPP/permlane/swizzle ----
    u32 h[4];
    h[0] = packf2(v[0], v[1]);
    h[1] = packf2(v[2], v[3]);
    h[2] = packf2(v[4], v[5]);
    h[3] = packf2(v[6], v[7]);

#pragma unroll
    for (int lk = 4; lk <= 11; ++lk) {
        const int k = 1 << lk;
        const bool up = ((tid & (k >> 3)) == 0);
#pragma unroll
        for (int lj = lk - 1; lj >= 3; --lj) {
            const int D = 1 << (lj - 3);
            const bool keepmin = (((tid & D) == 0) == up);
            if (D <= 32) {
#pragma unroll
                for (int m = 0; m < 4; ++m) {
                    u32 hs = lanexor(h[m], D, lo32);
                    u32 mn = pkmin(h[m], hs), mx = pkmax(h[m], hs);
                    h[m] = keepmin ? mn : mx;
                }
            } else {
                __syncthreads();
                *(uint4*)&sfu[tid * 4] = make_uint4(h[0], h[1], h[2], h[3]);
                __syncthreads();
                uint4 P = *(const uint4*)&sfu[(tid ^ D) * 4];
                h[0] = keepmin ? pkmin(h[0], P.x) : pkmax(h[0], P.x);
                h[1] = keepmin ? pkmin(h[1], P.y) : pkmax(h[1], P.y);
                h[2] = keepmin ? pkmin(h[2], P.z) : pkmax(h[2], P.z);
                h[3] = keepmin ? pkmin(h[3], P.w) : pkmax(h[3], P.w);
            }
        }
        merge8_pk(h, up);
    }

    // ---- unpack sorted values to f32 ----
    v[0] = unpk_lo(h[0]); v[1] = unpk_hi(h[0]);
    v[2] = unpk_lo(h[1]); v[3] = unpk_hi(h[1]);
    v[4] = unpk_lo(h[2]); v[5] = unpk_hi(h[2]);
    v[6] = unpk_lo(h[3]); v[7] = unpk_hi(h[3]);

    // ---- chunk-edge neighbors via shfl + wave-boundary LDS (no full staging) ----
    if (lane == 63) edgeA[wv] = v[7];
    if (lane == 0)  edgeB[wv] = v[0];
    __syncthreads();
    float lf1 = __shfl_up(v[7], 1);    // lane-1's v[7]  (lanes 1..63)
    float rt1 = __shfl_down(v[0], 1);  // lane+1's v[0]  (lanes 0..62)
    if (lane == 0)  lf1 = (wv == 0) ? 0.f : edgeA[wv - 1];
    if (lane == 63) rt1 = (wv == 3) ? 0.f : edgeB[wv + 1];
    if (tid == 0)   lf1 = 0.f;
    if (tid == 255) rt1 = 0.f;

    // ---- two half-row phases: conv1 -> h1t (bf16, swizzled) -> MFMA ----
    short8 afrag = *(const short8*)&a_lds[(lane & 15) * 32 + (lane >> 4) * 8];
    const int mb = (lane >> 4) * 4;
    const float bs0 = cb2[mb], bs1 = cb2[mb + 1], bs2 = cb2[mb + 2], bs3 = cb2[mb + 3];
    float s0 = 0.f, s1 = 0.f, s2 = 0.f, s3 = 0.f;
    f32x4 zero = {0.f, 0.f, 0.f, 0.f};

#pragma unroll 1
    for (int half = 0; half < 2; ++half) {
        __syncthreads();   // previous phase's LDS reads (sfu or MFMA) complete
        if ((tid >> 7) == half) {
            const int lt = tid & 127;
#pragma unroll
            for (int p = 0; p < 8; ++p) {
                float xm  = (p == 0) ? lf1 : v[p - 1];
                float x0v = v[p];
                float xp  = (p == 7) ? rt1 : v[p + 1];
                int uu = lt * 8 + p + 1;
                int us = uu ^ ((uu >> 3) & 7);
                *(short8*)&h1t[us * 8] = conv1pack(xm, x0v, xp, cw1, cb1);
            }
        }
        if (half == 0) {
            if (tid == 128)   // h1[1024] (slot 1025): xm=s[1023]=lf1
                *(short8*)&h1t[1025 * 8] = conv1pack(lf1, v[0], v[1], cw1, cb1);
            if (tid == 0) {   // h1[-1] = 0
                short8 z = {0, 0, 0, 0, 0, 0, 0, 0};
                *(short8*)&h1t[0] = z;
            }
            if (tid == 1) {   // d=3 overreach slots: must be finite (A row is 0)
                short8 z = {0, 0, 0, 0, 0, 0, 0, 0};
                *(short8*)&h1t[1026 * 8] = z;
                *(short8*)&h1t[1027 * 8] = z;
            }
        } else {
            if (tid == 127)   // h1[1023] (slot 0): xp=s[1024]=rt1
                *(short8*)&h1t[0] = conv1pack(v[6], v[7], rt1, cw1, cb1);
            if (tid == 0) {   // h1[2048] = 0
                short8 z = {0, 0, 0, 0, 0, 0, 0, 0};
                *(short8*)&h1t[1025 * 8] = z;
            }
        }
        __syncthreads();

#pragma unroll 4
        for (int i = 0; i < 16; ++i) {
            int lp = (wv * 16 + i) * 16 + (lane & 15);   // local position 0..1023
            int uu = lp + (lane >> 4);                   // slot = local_pos + d
            int us = uu ^ ((uu >> 3) & 7);
            short8 bfrag = *(const short8*)&h1t[us * 8];
            f32x4 d = __builtin_amdgcn_mfma_f32_16x16x32_bf16(afrag, bfrag, zero, 0, 0, 0);
            s0 += fmaxf(d[0] + bs0, 0.f);
            s1 += fmaxf(d[1] + bs1, 0.f);
            s2 += fmaxf(d[2] + bs2, 0.f);
            s3 += fmaxf(d[3] + bs3, 0.f);
        }
    }

    // ---- reduce over the 16 column-lanes (positions) ----
#pragma unroll
    for (int off = 1; off < 16; off <<= 1) {
        s0 += __shfl_xor(s0, off);
        s1 += __shfl_xor(s1, off);
        s2 += __shfl_xor(s2, off);
        s3 += __shfl_xor(s3, off);
    }
    if ((lane & 15) == 0) {
        red[wv][mb + 0] = s0; red[wv][mb + 1] = s1;
        red[wv][mb + 2] = s2; red[wv][mb + 3] = s3;
    }
    if (tid < 128) u[tid] = myagg;
    __syncthreads();

    // ---- readout = mean @ Wr + br ----
    if (tid < 8) {
        float acc = br[tid];
#pragma unroll
        for (int c = 0; c < 16; ++c) {
            float tot = red[0][c] + red[1][c] + red[2][c] + red[3][c];
            acc += (tot * (1.0f / (float)LROW)) * Wr[c * 8 + tid];
        }
        u[128 + tid] = acc;
    }
    __syncthreads();

    // ---- lin1: t[r] = concat(aggx, readout) @ W1 + b1 ----
    {
        const int jc = tid & 127, hf = tid >> 7;
        float acc = (hf == 0) ? b1[jc] : 0.f;
        const int c0 = hf * 68;
#pragma unroll 4
        for (int c = 0; c < 68; ++c) acc += u[c0 + c] * W1[(size_t)(c0 + c) * 128 + jc];
        if (hf) lpart[jc] = acc;
        __syncthreads();
        if (!hf) t[(size_t)r * 128 + jc] = acc + lpart[jc];
    }
}

// ---------------- BN stats stage 1, coalesced, deterministic ----------------

__global__ __launch_bounds__(256) void bnpart_k(const float* __restrict__ t,
                                                float* __restrict__ part) {
    const int b = blockIdx.x, tid = threadIdx.x;
    const int col = tid & 127, h = tid >> 7;
    float sm = 0.f, sq = 0.f;
    for (int i = 0; i < 32; ++i) {
        int row = b * 64 + h * 32 + i;
        float v = t[(size_t)row * 128 + col];
        sm += v; sq += v * v;
    }
    __shared__ float ps[2][128], pq[2][128];
    ps[h][col] = sm; pq[h][col] = sq;
    __syncthreads();
    if (h == 0) {
        part[(size_t)b * 256 + col]       = sm + ps[1][col];
        part[(size_t)b * 256 + 128 + col] = sq + pq[1][col];
    }
}

// ---------------- BN finalize (inline) + ReLU + @W2 + b2, 16 rows/block ----------

__global__ __launch_bounds__(256) void out_k(
        float* __restrict__ t, const float* __restrict__ part,
        const float* __restrict__ gamma, const float* __restrict__ beta,
        const float* __restrict__ W2, const float* __restrict__ b2) {
    __shared__ float u[16][128];
    __shared__ float sc_s[128], sh_s[128];
    const int r0 = blockIdx.x * 16, tid = threadIdx.x;
    if (tid < 128) {
        float sm = 0.f, sq = 0.f;
        for (int b = 0; b < 32; ++b) {
            sm += part[(size_t)b * 256 + tid];
            sq += part[(size_t)b * 256 + 128 + tid];
        }
        float mu  = sm / (float)NN;
        float var = sq / (float)NN - mu * mu;
        float sc  = rsqrtf(var + 1e-5f) * gamma[tid];
        sc_s[tid] = sc;
        sh_s[tid] = beta[tid] - mu * sc;
    }
    __syncthreads();
#pragma unroll
    for (int m = 0; m < 8; ++m) {
        int idx = tid + 256 * m;
        int rr = idx >> 7, c = idx & 127;
        float v = t[(size_t)(r0 + rr) * 128 + c];
        v = v * sc_s[c] + sh_s[c];
        u[rr][c] = v > 0.f ? v : 0.f;
    }
    __syncthreads();
    const int j = tid & 127, g = tid >> 7;
    float acc[8];
    float bb = b2[j];
#pragma unroll
    for (int rr = 0; rr < 8; ++rr) acc[rr] = bb;
    for (int c = 0; c < 128; ++c) {
        float w = W2[(size_t)c * 128 + j];
#pragma unroll
        for (int rr = 0; rr < 8; ++rr) acc[rr] += u[g * 8 + rr][c] * w;
    }
#pragma unroll
    for (int rr = 0; rr < 8; ++rr)
        t[(size_t)(r0 + g * 8 + rr) * 128 + j] = acc[rr];
}

// ---------------- launch ----------------

extern "C" void kernel_launch(void* const* d_in, const int* in_sizes, int n_in,
                              void* d_out, int out_size, void* d_ws, size_t ws_size,
                              hipStream_t stream) {
    const float* x      = (const float*)d_in[0];
    const float* onehot = (const float*)d_in[1];
    const int*   adj    = (const int*)d_in[2];
    // d_in[3] = n_nodes (scalar), fixed at 2048
    const float* W1     = (const float*)d_in[4];
    const float* b1     = (const float*)d_in[5];
    const float* gamma  = (const float*)d_in[6];
    const float* beta   = (const float*)d_in[7];
    const float* W2     = (const float*)d_in[8];
    const float* b2     = (const float*)d_in[9];
    const float* cw1    = (const float*)d_in[10];
    const float* cb1    = (const float*)d_in[11];
    const float* cw2    = (const float*)d_in[12];
    const float* cb2    = (const float*)d_in[13];
    const float* Wr     = (const float*)d_in[14];
    const float* br     = (const float*)d_in[15];

    const int E = in_sizes[2] / 2;
    const int* send = adj;
    const int* recv = adj + E;

    // workspace layout
    int*   cnt    = (int*)d_ws;                          // 2048 ints
    int*   elist2 = cnt + 2048;                          // 2048*DEGCAP ints
    float* part   = (float*)(elist2 + NN * DEGCAP);      // 32*256
    unsigned short* ohbf = (unsigned short*)(part + 32 * 256);  // 2048*2048 bf16
    size_t need = (size_t)((char*)(ohbf + (size_t)NN * LROW) - (char*)d_ws);
    const bool bf_path = (ws_size >= need);

    float* out_x2 = (float*)d_out;              // [2048,128] (staged pre-BN, then final)
    float* out_oh = out_x2 + (size_t)NN * 128;  // [2048,2048]

    hipMemsetAsync(cnt, 0, 2048 * sizeof(int), stream);

    if (bf_path) {
        prep_k<<<NN + (E + 255) / 256, 256, 0, stream>>>(onehot, ohbf, send, recv,
                                                         cnt, elist2, E);
        fused_k<1><<<NN, 256, 0, stream>>>(onehot, ohbf, x, elist2, cnt,
                                           out_oh, out_x2,
                                           cw1, cb1, cw2, cb2, Wr, br, W1, b1);
    } else {
        prep_k<<<NN + (E + 255) / 256, 256, 0, stream>>>(onehot, ohbf, send, recv,
                                                         cnt, elist2, E);
        fused_k<0><<<NN, 256, 0, stream>>>(onehot, ohbf, x, elist2, cnt,
                                           out_oh, out_x2,
                                           cw1, cb1, cw2, cb2, Wr, br, W1, b1);
    }
    bnpart_k<<<32, 256, 0, stream>>>(out_x2, part);
    out_k<<<NN / 16, 256, 0, stream>>>(out_x2, part, gamma, beta, W2, b2);
}